// Round 4
// baseline (1032.248 us; speedup 1.0000x reference)
//
#include <hip/hip_runtime.h>

// ---------------------------------------------------------------------------
// 2-layer GAT (PyG GATConv), fp32, MI355X.
// R4: (1) CSR back to multi-kernel (R3 cooperative kernel was 224us of
//     grid.sync stall). (2) Edge softmax weights precomputed edge-parallel
//     (no max-shift needed: |logit| <~15, exp can't overflow fp32) ->
//     k_aggr is pure gather+FMA. (3) aggr keeps octet XCD split; with
//     per-half weight arrays the duplicated work is ~zero; per-XCD h
//     footprint halves -> FETCH ~215 MB predicted. (4) GEMM: no breg[8][8]
//     register panel (spill risk); B loaded per-kk from L1-resident panel.
// ---------------------------------------------------------------------------

__global__ __launch_bounds__(256)
void k_hist(const int* __restrict__ dstv, int* __restrict__ cnt, int E) {
  int i = blockIdx.x * 256 + threadIdx.x;
  if (i < E) atomicAdd(&cnt[dstv[i]], 1);
}

__global__ __launch_bounds__(256)
void k_scan_local(const int* __restrict__ cnt, int* __restrict__ rowptr,
                  int* __restrict__ partials, int N) {
  __shared__ int sm[256];
  int gid = blockIdx.x * 256 + threadIdx.x;
  int v = (gid < N) ? cnt[gid] : 0;
  sm[threadIdx.x] = v;
  __syncthreads();
  for (int off = 1; off < 256; off <<= 1) {
    int t = (threadIdx.x >= (unsigned)off) ? sm[threadIdx.x - off] : 0;
    __syncthreads();
    sm[threadIdx.x] += t;
    __syncthreads();
  }
  if (gid < N) rowptr[gid] = sm[threadIdx.x] - v;  // exclusive
  if (threadIdx.x == 255) partials[blockIdx.x] = sm[255];
}

__global__ __launch_bounds__(256)
void k_scan_part(int* __restrict__ partials, int nb) {
  __shared__ int sm[256];
  int t = threadIdx.x;
  int v = (t < nb) ? partials[t] : 0;
  sm[t] = v;
  __syncthreads();
  for (int off = 1; off < 256; off <<= 1) {
    int u = (t >= off) ? sm[t - off] : 0;
    __syncthreads();
    sm[t] += u;
    __syncthreads();
  }
  if (t < nb) partials[t] = sm[t] - v;  // exclusive
}

__global__ __launch_bounds__(256)
void k_scan_add(int* __restrict__ rowptr, const int* __restrict__ partials,
                int* __restrict__ cursor, int N, int E) {
  int gid = blockIdx.x * 256 + threadIdx.x;
  if (gid < N) {
    int rp = rowptr[gid] + partials[blockIdx.x];
    rowptr[gid] = rp;
    cursor[gid] = rp;
  }
  if (gid == 0) rowptr[N] = E;
}

__global__ __launch_bounds__(256)
void k_scatter(const int* __restrict__ srcv, const int* __restrict__ dstv,
               int* __restrict__ cursor, int* __restrict__ col,
               int* __restrict__ rowid, int E) {
  int i = blockIdx.x * 256 + threadIdx.x;
  if (i < E) {
    int d = dstv[i];
    int p = atomicAdd(&cursor[d], 1);
    col[p] = srcv[i];
    rowid[p] = d;
  }
}

// ---------------------------------------------------------------------------
// fp32 GEMM: C[N,256] = A[N,K] @ W[K,256]. 128x128 tile, 16x16 threads, 8x8
// microtile. A transposed in LDS; B loaded per-kk from the L1-resident 4KB
// panel (no 64-VGPR register panel). Fused attention-score epilogue:
// a_s[n,h] = sum_c h[n,c]*att_s[c] via 8-lane butterfly + device atomicAdd
// (a_s/a_d pre-zeroed).
// ---------------------------------------------------------------------------
__global__ __launch_bounds__(256)
void k_gemm(const float* __restrict__ A, const float* __restrict__ W,
            float* __restrict__ C, int Nrows, int K,
            const float* __restrict__ att_s, const float* __restrict__ att_d,
            float* __restrict__ a_s, float* __restrict__ a_d) {
  __shared__ float At[8][132];
  const int tx = threadIdx.x & 15;
  const int ty = threadIdx.x >> 4;
  const int row0 = blockIdx.x * 128;
  const int col0 = blockIdx.y * 128;
  const int arow = threadIdx.x >> 1;
  const int akk  = (threadIdx.x & 1) * 4;

  float acc[8][8] = {};

  for (int k0 = 0; k0 < K; k0 += 8) {
    int gr = row0 + arow;
    float4 av = make_float4(0.f, 0.f, 0.f, 0.f);
    if (gr < Nrows) av = *(const float4*)(A + (size_t)gr * K + k0 + akk);
    At[akk + 0][arow] = av.x;
    At[akk + 1][arow] = av.y;
    At[akk + 2][arow] = av.z;
    At[akk + 3][arow] = av.w;
    __syncthreads();
#pragma unroll
    for (int kk = 0; kk < 8; kk++) {
      const float* wp = W + (size_t)(k0 + kk) * 256 + col0 + tx * 8;
      float4 b0 = *(const float4*)(wp);
      float4 b1 = *(const float4*)(wp + 4);
      float br[8] = {b0.x, b0.y, b0.z, b0.w, b1.x, b1.y, b1.z, b1.w};
      float4 a0 = *(const float4*)(&At[kk][ty * 8]);
      float4 a1 = *(const float4*)(&At[kk][ty * 8 + 4]);
      float ar[8] = {a0.x, a0.y, a0.z, a0.w, a1.x, a1.y, a1.z, a1.w};
#pragma unroll
      for (int i = 0; i < 8; i++)
#pragma unroll
        for (int j = 0; j < 8; j++)
          acc[i][j] += ar[i] * br[j];
    }
    __syncthreads();
  }

#pragma unroll
  for (int i = 0; i < 8; i++) {
    int gr = row0 + ty * 8 + i;
    if (gr < Nrows) {
      float* cp = C + (size_t)gr * 256 + col0 + tx * 8;
      *(float4*)(cp)     = make_float4(acc[i][0], acc[i][1], acc[i][2], acc[i][3]);
      *(float4*)(cp + 4) = make_float4(acc[i][4], acc[i][5], acc[i][6], acc[i][7]);
    }
  }

  // ---- fused attention-score epilogue
  const int cbase = col0 + tx * 8;
  float asv[8], adv[8];
#pragma unroll
  for (int j = 0; j < 8; j++) { asv[j] = att_s[cbase + j]; adv[j] = att_d[cbase + j]; }
  const int head = cbase >> 6;  // tx*8 never straddles a 64-col boundary
#pragma unroll
  for (int i = 0; i < 8; i++) {
    float ps = 0.f, pd = 0.f;
#pragma unroll
    for (int j = 0; j < 8; j++) { ps += acc[i][j] * asv[j]; pd += acc[i][j] * adv[j]; }
    ps += __shfl_xor(ps, 1); pd += __shfl_xor(pd, 1);
    ps += __shfl_xor(ps, 2); pd += __shfl_xor(pd, 2);
    ps += __shfl_xor(ps, 4); pd += __shfl_xor(pd, 4);
    if ((tx & 7) == 0) {
      int gr = row0 + ty * 8 + i;
      if (gr < Nrows) {
        atomicAdd(&a_s[(size_t)gr * 4 + head], ps);
        atomicAdd(&a_d[(size_t)gr * 4 + head], pd);
      }
    }
  }
}

// ---------------------------------------------------------------------------
// Edge weights, edge-parallel over CSR slots: w = exp(leaky(a_s[src]+a_d[dst]))
// (no max-shift: |logit| small, fp32 exp safe), denom via atomicAdd.
// wA holds heads {0,1}, wB heads {2,3} (per-half coalesced reads in k_aggr).
// ---------------------------------------------------------------------------
__global__ __launch_bounds__(256)
void k_edge(const int* __restrict__ col, const int* __restrict__ rowid,
            const float* __restrict__ a_s, const float* __restrict__ a_d,
            float* __restrict__ wA, float* __restrict__ wB,
            float* __restrict__ den, int E) {
  int p = blockIdx.x * 256 + threadIdx.x;
  if (p >= E) return;
  int s = col[p], d = rowid[p];
  float4 as4 = *(const float4*)(a_s + (size_t)s * 4);
  float4 ad4 = *(const float4*)(a_d + (size_t)d * 4);
  float e0 = as4.x + ad4.x; e0 = e0 > 0.f ? e0 : 0.2f * e0;
  float e1 = as4.y + ad4.y; e1 = e1 > 0.f ? e1 : 0.2f * e1;
  float e2 = as4.z + ad4.z; e2 = e2 > 0.f ? e2 : 0.2f * e2;
  float e3 = as4.w + ad4.w; e3 = e3 > 0.f ? e3 : 0.2f * e3;
  float w0 = __expf(e0), w1 = __expf(e1), w2 = __expf(e2), w3 = __expf(e3);
  *(float2*)(wA + (size_t)p * 2) = make_float2(w0, w1);
  *(float2*)(wB + (size_t)p * 2) = make_float2(w2, w3);
  float* dn = den + (size_t)d * 4;
  atomicAdd(dn + 0, w0);
  atomicAdd(dn + 1, w1);
  atomicAdd(dn + 2, w2);
  atomicAdd(dn + 3, w3);
}

// ---------------------------------------------------------------------------
// Aggregation: one wave per (node, channel-half); octet mapping blockIdx%8:
// slots 0..3 -> half 0 (heads 0,1), 4..7 -> half 1 (heads 2,3). With
// round-robin block->XCD placement each XCD touches only half of h.
// Pure gather+FMA: weights precomputed, denom applied at the end.
// LAYER 1: relu(acc/den + bias) -> [N,256]. LAYER 2: acc/den -> temp [N,256].
// ---------------------------------------------------------------------------
template <int LAYER>
__global__ __launch_bounds__(256)
void k_aggr(const float* __restrict__ hsrc, const int* __restrict__ rowptr,
            const int* __restrict__ col, const float* __restrict__ wA,
            const float* __restrict__ wB, const float* __restrict__ den,
            const float* __restrict__ bias, float* __restrict__ outp, int N) {
  __shared__ int   s_sh[4][64];
  __shared__ float w_sh[4][128];
  const int wv = threadIdx.x >> 6;
  const int lane = threadIdx.x & 63;
  const int g = blockIdx.x >> 3;
  const int s8 = blockIdx.x & 7;
  const int half = s8 >> 2;
  const int node = g * 16 + (s8 & 3) * 4 + wv;
  if (node >= N) return;
  const int hd = lane >> 5;  // head within half
  const int beg = rowptr[node], end = rowptr[node + 1];
  const float* wH = half ? wB : wA;

  float2 acc = make_float2(0.f, 0.f);

  for (int c0 = beg; c0 < end; c0 += 64) {
    int nc = min(64, end - c0);
    int s = 0;
    float2 wv2 = make_float2(0.f, 0.f);
    if (lane < nc) {
      s = col[c0 + lane];
      wv2 = *(const float2*)(wH + (size_t)(c0 + lane) * 2);
    }
    s_sh[wv][lane] = s;
    *(float2*)(&w_sh[wv][lane * 2]) = wv2;
    asm volatile("s_waitcnt lgkmcnt(0)" ::: "memory");

    const float* wrow = &w_sh[wv][hd];
    const int*   srow = &s_sh[wv][0];
    const float* hbase = hsrc + half * 128 + lane * 2;
    int j = 0;
    for (; j + 4 <= nc; j += 4) {
      int sj0 = srow[j], sj1 = srow[j + 1], sj2 = srow[j + 2], sj3 = srow[j + 3];
      float w0 = wrow[2 * j], w1 = wrow[2 * j + 2];
      float w2 = wrow[2 * j + 4], w3 = wrow[2 * j + 6];
      float2 h0 = *(const float2*)(hbase + (size_t)sj0 * 256);
      float2 h1 = *(const float2*)(hbase + (size_t)sj1 * 256);
      float2 h2 = *(const float2*)(hbase + (size_t)sj2 * 256);
      float2 h3 = *(const float2*)(hbase + (size_t)sj3 * 256);
      acc.x += w0 * h0.x; acc.y += w0 * h0.y;
      acc.x += w1 * h1.x; acc.y += w1 * h1.y;
      acc.x += w2 * h2.x; acc.y += w2 * h2.y;
      acc.x += w3 * h3.x; acc.y += w3 * h3.y;
    }
    for (; j < nc; j++) {
      int sj = srow[j];
      float w = wrow[2 * j];
      float2 hv = *(const float2*)(hbase + (size_t)sj * 256);
      acc.x += w * hv.x; acc.y += w * hv.y;
    }
  }

  const float2 dn = *(const float2*)(den + (size_t)node * 4 + half * 2);
  float inv = 1.0f / (hd ? dn.y : dn.x);  // deg>=1 via self-loop
  float2 v = make_float2(acc.x * inv, acc.y * inv);
  const size_t o = (size_t)node * 256 + half * 128 + lane * 2;
  if (LAYER == 1) {
    float2 bv = *(const float2*)(bias + half * 128 + lane * 2);
    v.x = fmaxf(v.x + bv.x, 0.f);
    v.y = fmaxf(v.y + bv.y, 0.f);
    *(float2*)(outp + o) = v;
  } else {
    *(float2*)(outp + o) = v;  // per-head normalized values; k_final mixes
  }
}

// ---------------------------------------------------------------------------
// Layer-2 epilogue: head-mean + bias + relu + softmax(64). One wave per node.
// ---------------------------------------------------------------------------
__global__ __launch_bounds__(256)
void k_final(const float* __restrict__ t, const float* __restrict__ b2,
             float* __restrict__ out, int N) {
  int node = (int)((blockIdx.x * 256u + threadIdx.x) >> 6);
  int lane = threadIdx.x & 63;
  if (node >= N) return;
  const float* tr = t + (size_t)node * 256;
  float v = 0.25f * (tr[lane] + tr[64 + lane] + tr[128 + lane] + tr[192 + lane]) + b2[lane];
  v = fmaxf(v, 0.f);
  float mx = v;
  for (int off = 32; off; off >>= 1) mx = fmaxf(mx, __shfl_xor(mx, off));
  float e = __expf(v - mx);
  float sum = e;
  for (int off = 32; off; off >>= 1) sum += __shfl_xor(sum, off);
  out[(size_t)node * 64 + lane] = e / sum;
}

// ---------------------------------------------------------------------------

extern "C" void kernel_launch(void* const* d_in, const int* in_sizes, int n_in,
                              void* d_out, int out_size, void* d_ws, size_t ws_size,
                              hipStream_t stream) {
  const float* x   = (const float*)d_in[0];
  const int*   ei  = (const int*)d_in[1];
  const float* W1  = (const float*)d_in[2];
  const float* as1 = (const float*)d_in[3];
  const float* ad1 = (const float*)d_in[4];
  const float* b1  = (const float*)d_in[5];
  const float* W2  = (const float*)d_in[6];
  const float* as2 = (const float*)d_in[7];
  const float* ad2 = (const float*)d_in[8];
  const float* b2  = (const float*)d_in[9];
  float* out = (float*)d_out;

  const int N = in_sizes[0] / 128;
  const int E = in_sizes[1] / 2;
  const int* srcv = ei;
  const int* dstv = ei + E;

  float* h    = (float*)d_ws;             // [N,256]
  float* hb   = h + (size_t)N * 256;      // [N,256] (layer-1 out / layer-2 temp)
  float* zbuf = hb + (size_t)N * 256;     // 24N: a_s1,a_d1,den1,a_s2,a_d2,den2
  float* a_s1 = zbuf;
  float* a_d1 = a_s1 + (size_t)N * 4;
  float* den1 = a_d1 + (size_t)N * 4;
  float* a_s2 = den1 + (size_t)N * 4;
  float* a_d2 = a_s2 + (size_t)N * 4;
  float* den2 = a_d2 + (size_t)N * 4;
  int*   rowptr = (int*)(zbuf + (size_t)N * 24);  // [N+1] (+pad)
  int*   cnt    = rowptr + (N + 4);               // [N]
  int*   cursor = cnt + N;                        // [N]
  int*   col    = cursor + N;                     // [E]
  int*   rowid  = col + E;                        // [E]
  float* wA     = (float*)(rowid + E);            // [E,2] heads 0,1
  float* wB     = wA + (size_t)E * 2;             // [E,2] heads 2,3
  int*   partials = (int*)(wB + (size_t)E * 2);   // [<=256]

  const int nb = (N + 255) / 256;
  const int eb = (E + 255) / 256;

  hipMemsetAsync(cnt, 0, (size_t)N * 4, stream);
  hipMemsetAsync(zbuf, 0, (size_t)N * 24 * 4, stream);
  k_hist<<<eb, 256, 0, stream>>>(dstv, cnt, E);
  k_scan_local<<<nb, 256, 0, stream>>>(cnt, rowptr, partials, N);
  k_scan_part<<<1, 256, 0, stream>>>(partials, nb);
  k_scan_add<<<nb, 256, 0, stream>>>(rowptr, partials, cursor, N, E);
  k_scatter<<<eb, 256, 0, stream>>>(srcv, dstv, cursor, col, rowid, E);

  dim3 gg((N + 127) / 128, 2);
  const int ab = ((N + 15) / 16) * 8;  // octet-mapped (node, half) waves
  const int wb = (N + 3) / 4;          // wave-per-node

  k_gemm<<<gg, 256, 0, stream>>>(x, W1, h, N, 128, as1, ad1, a_s1, a_d1);
  k_edge<<<eb, 256, 0, stream>>>(col, rowid, a_s1, a_d1, wA, wB, den1, E);
  k_aggr<1><<<ab, 256, 0, stream>>>(h, rowptr, col, wA, wB, den1, b1, hb, N);
  k_gemm<<<gg, 256, 0, stream>>>(hb, W2, h, N, 256, as2, ad2, a_s2, a_d2);
  k_edge<<<eb, 256, 0, stream>>>(col, rowid, a_s2, a_d2, wA, wB, den2, E);
  k_aggr<2><<<ab, 256, 0, stream>>>(h, rowptr, col, wA, wB, den2, b2, hb, N);
  k_final<<<wb, 256, 0, stream>>>(hb, b2, out, N);
}

// Round 5
// 641.175 us; speedup vs baseline: 1.6099x; 1.6099x over previous
//
#include <hip/hip_runtime.h>

// ---------------------------------------------------------------------------
// 2-layer GAT (PyG GATConv), fp32, MI355X.
// R5: k_edge DELETED (its den-atomicAdd serialized ~16-way on the dst-sorted
//     CSR -> 208us). Weights computed inline in k_aggr's chunk stage
//     (a_s gather from 800KB L2-resident table + 2 expf); denominator
//     accumulated for free in the j-loop (every lane already reads every
//     edge weight of its head). No max-shift (logits ~N(0,2); R4 validated).
//     Octet XCD split kept: blockIdx%8 slots 0-3 -> channels 0-127,
//     4-7 -> 128-255; per-XCD h footprint halves.
// ---------------------------------------------------------------------------

__global__ __launch_bounds__(256)
void k_hist(const int* __restrict__ dstv, int* __restrict__ cnt, int E) {
  int i = blockIdx.x * 256 + threadIdx.x;
  if (i < E) atomicAdd(&cnt[dstv[i]], 1);
}

__global__ __launch_bounds__(256)
void k_scan_local(const int* __restrict__ cnt, int* __restrict__ rowptr,
                  int* __restrict__ partials, int N) {
  __shared__ int sm[256];
  int gid = blockIdx.x * 256 + threadIdx.x;
  int v = (gid < N) ? cnt[gid] : 0;
  sm[threadIdx.x] = v;
  __syncthreads();
  for (int off = 1; off < 256; off <<= 1) {
    int t = (threadIdx.x >= (unsigned)off) ? sm[threadIdx.x - off] : 0;
    __syncthreads();
    sm[threadIdx.x] += t;
    __syncthreads();
  }
  if (gid < N) rowptr[gid] = sm[threadIdx.x] - v;  // exclusive
  if (threadIdx.x == 255) partials[blockIdx.x] = sm[255];
}

__global__ __launch_bounds__(256)
void k_scan_part(int* __restrict__ partials, int nb) {
  __shared__ int sm[256];
  int t = threadIdx.x;
  int v = (t < nb) ? partials[t] : 0;
  sm[t] = v;
  __syncthreads();
  for (int off = 1; off < 256; off <<= 1) {
    int u = (t >= off) ? sm[t - off] : 0;
    __syncthreads();
    sm[t] += u;
    __syncthreads();
  }
  if (t < nb) partials[t] = sm[t] - v;  // exclusive
}

__global__ __launch_bounds__(256)
void k_scan_add(int* __restrict__ rowptr, const int* __restrict__ partials,
                int* __restrict__ cursor, int N, int E) {
  int gid = blockIdx.x * 256 + threadIdx.x;
  if (gid < N) {
    int rp = rowptr[gid] + partials[blockIdx.x];
    rowptr[gid] = rp;
    cursor[gid] = rp;
  }
  if (gid == 0) rowptr[N] = E;
}

__global__ __launch_bounds__(256)
void k_scatter(const int* __restrict__ srcv, const int* __restrict__ dstv,
               int* __restrict__ cursor, int* __restrict__ col, int E) {
  int i = blockIdx.x * 256 + threadIdx.x;
  if (i < E) {
    int p = atomicAdd(&cursor[dstv[i]], 1);
    col[p] = srcv[i];
  }
}

// ---------------------------------------------------------------------------
// fp32 GEMM: C[N,256] = A[N,K] @ W[K,256]. 128x128 tile, 16x16 threads, 8x8
// microtile. A transposed in LDS; B per-kk from L1-resident 4KB panel.
// Fused attention-score epilogue (8-lane butterfly + atomicAdd; a_s/a_d
// pre-zeroed; per-(row,head) address touched by exactly 2 blocks -> no
// contention issue).
// ---------------------------------------------------------------------------
__global__ __launch_bounds__(256)
void k_gemm(const float* __restrict__ A, const float* __restrict__ W,
            float* __restrict__ C, int Nrows, int K,
            const float* __restrict__ att_s, const float* __restrict__ att_d,
            float* __restrict__ a_s, float* __restrict__ a_d) {
  __shared__ float At[8][132];
  const int tx = threadIdx.x & 15;
  const int ty = threadIdx.x >> 4;
  const int row0 = blockIdx.x * 128;
  const int col0 = blockIdx.y * 128;
  const int arow = threadIdx.x >> 1;
  const int akk  = (threadIdx.x & 1) * 4;

  float acc[8][8] = {};

  for (int k0 = 0; k0 < K; k0 += 8) {
    int gr = row0 + arow;
    float4 av = make_float4(0.f, 0.f, 0.f, 0.f);
    if (gr < Nrows) av = *(const float4*)(A + (size_t)gr * K + k0 + akk);
    At[akk + 0][arow] = av.x;
    At[akk + 1][arow] = av.y;
    At[akk + 2][arow] = av.z;
    At[akk + 3][arow] = av.w;
    __syncthreads();
#pragma unroll
    for (int kk = 0; kk < 8; kk++) {
      const float* wp = W + (size_t)(k0 + kk) * 256 + col0 + tx * 8;
      float4 b0 = *(const float4*)(wp);
      float4 b1 = *(const float4*)(wp + 4);
      float br[8] = {b0.x, b0.y, b0.z, b0.w, b1.x, b1.y, b1.z, b1.w};
      float4 a0 = *(const float4*)(&At[kk][ty * 8]);
      float4 a1 = *(const float4*)(&At[kk][ty * 8 + 4]);
      float ar[8] = {a0.x, a0.y, a0.z, a0.w, a1.x, a1.y, a1.z, a1.w};
#pragma unroll
      for (int i = 0; i < 8; i++)
#pragma unroll
        for (int j = 0; j < 8; j++)
          acc[i][j] += ar[i] * br[j];
    }
    __syncthreads();
  }

#pragma unroll
  for (int i = 0; i < 8; i++) {
    int gr = row0 + ty * 8 + i;
    if (gr < Nrows) {
      float* cp = C + (size_t)gr * 256 + col0 + tx * 8;
      *(float4*)(cp)     = make_float4(acc[i][0], acc[i][1], acc[i][2], acc[i][3]);
      *(float4*)(cp + 4) = make_float4(acc[i][4], acc[i][5], acc[i][6], acc[i][7]);
    }
  }

  // ---- fused attention-score epilogue
  const int cbase = col0 + tx * 8;
  float asv[8], adv[8];
#pragma unroll
  for (int j = 0; j < 8; j++) { asv[j] = att_s[cbase + j]; adv[j] = att_d[cbase + j]; }
  const int head = cbase >> 6;  // tx*8 never straddles a 64-col boundary
#pragma unroll
  for (int i = 0; i < 8; i++) {
    float ps = 0.f, pd = 0.f;
#pragma unroll
    for (int j = 0; j < 8; j++) { ps += acc[i][j] * asv[j]; pd += acc[i][j] * adv[j]; }
    ps += __shfl_xor(ps, 1); pd += __shfl_xor(pd, 1);
    ps += __shfl_xor(ps, 2); pd += __shfl_xor(pd, 2);
    ps += __shfl_xor(ps, 4); pd += __shfl_xor(pd, 4);
    if ((tx & 7) == 0) {
      int gr = row0 + ty * 8 + i;
      if (gr < Nrows) {
        atomicAdd(&a_s[(size_t)gr * 4 + head], ps);
        atomicAdd(&a_d[(size_t)gr * 4 + head], pd);
      }
    }
  }
}

// ---------------------------------------------------------------------------
// Aggregation: one wave per (node, channel-half); octet mapping blockIdx%8:
// slots 0..3 -> half 0 (heads 0,1), 4..7 -> half 1 (heads 2,3).
// Chunk stage: lane gathers a_s[col] (float2, L2-resident 800KB), computes
// w = exp(leaky(a_s+a_d)) inline, stages (src,w) in LDS. j-loop: gather h
// rows + FMA; denominator accumulated from the staged weights (free).
// LAYER 1: relu(acc/den + bias) -> [N,256]. LAYER 2: acc/den -> temp.
// ---------------------------------------------------------------------------
template <int LAYER>
__global__ __launch_bounds__(256)
void k_aggr(const float* __restrict__ hsrc, const int* __restrict__ rowptr,
            const int* __restrict__ col, const float* __restrict__ a_s,
            const float* __restrict__ a_d, const float* __restrict__ bias,
            float* __restrict__ outp, int N) {
  __shared__ int   s_sh[4][64];
  __shared__ float w_sh[4][128];
  const int wv = threadIdx.x >> 6;
  const int lane = threadIdx.x & 63;
  const int g = blockIdx.x >> 3;
  const int s8 = blockIdx.x & 7;
  const int half = s8 >> 2;
  const int node = g * 16 + (s8 & 3) * 4 + wv;
  if (node >= N) return;
  const int hd = lane >> 5;  // head within half
  const int beg = rowptr[node], end = rowptr[node + 1];
  const float2 adst = *(const float2*)(a_d + (size_t)node * 4 + half * 2);

  float2 acc = make_float2(0.f, 0.f);
  float wsum = 0.f;

  for (int c0 = beg; c0 < end; c0 += 64) {
    int nc = min(64, end - c0);
    int s = 0;
    float w0 = 0.f, w1 = 0.f;
    if (lane < nc) {
      s = col[c0 + lane];
      float2 asr = *(const float2*)(a_s + (size_t)s * 4 + half * 2);
      float e0 = asr.x + adst.x; e0 = e0 > 0.f ? e0 : 0.2f * e0;
      float e1 = asr.y + adst.y; e1 = e1 > 0.f ? e1 : 0.2f * e1;
      w0 = __expf(e0); w1 = __expf(e1);
    }
    s_sh[wv][lane] = s;
    *(float2*)(&w_sh[wv][lane * 2]) = make_float2(w0, w1);
    asm volatile("s_waitcnt lgkmcnt(0)" ::: "memory");

    const float* wrow = &w_sh[wv][hd];
    const int*   srow = &s_sh[wv][0];
    const float* hbase = hsrc + half * 128 + lane * 2;
    int j = 0;
    for (; j + 4 <= nc; j += 4) {
      int sj0 = srow[j], sj1 = srow[j + 1], sj2 = srow[j + 2], sj3 = srow[j + 3];
      float ww0 = wrow[2 * j],     ww1 = wrow[2 * j + 2];
      float ww2 = wrow[2 * j + 4], ww3 = wrow[2 * j + 6];
      float2 h0 = *(const float2*)(hbase + (size_t)sj0 * 256);
      float2 h1 = *(const float2*)(hbase + (size_t)sj1 * 256);
      float2 h2 = *(const float2*)(hbase + (size_t)sj2 * 256);
      float2 h3 = *(const float2*)(hbase + (size_t)sj3 * 256);
      wsum += ww0 + ww1 + ww2 + ww3;
      acc.x += ww0 * h0.x; acc.y += ww0 * h0.y;
      acc.x += ww1 * h1.x; acc.y += ww1 * h1.y;
      acc.x += ww2 * h2.x; acc.y += ww2 * h2.y;
      acc.x += ww3 * h3.x; acc.y += ww3 * h3.y;
    }
    for (; j < nc; j++) {
      int sj = srow[j];
      float w = wrow[2 * j];
      float2 hv = *(const float2*)(hbase + (size_t)sj * 256);
      wsum += w;
      acc.x += w * hv.x; acc.y += w * hv.y;
    }
  }

  float inv = 1.0f / wsum;  // deg>=1 via self-loop => wsum>0
  float2 v = make_float2(acc.x * inv, acc.y * inv);
  const size_t o = (size_t)node * 256 + half * 128 + lane * 2;
  if (LAYER == 1) {
    float2 bv = *(const float2*)(bias + half * 128 + lane * 2);
    v.x = fmaxf(v.x + bv.x, 0.f);
    v.y = fmaxf(v.y + bv.y, 0.f);
    *(float2*)(outp + o) = v;
  } else {
    *(float2*)(outp + o) = v;  // per-head normalized values; k_final mixes
  }
}

// ---------------------------------------------------------------------------
// Layer-2 epilogue: head-mean + bias + relu + softmax(64). One wave per node.
// ---------------------------------------------------------------------------
__global__ __launch_bounds__(256)
void k_final(const float* __restrict__ t, const float* __restrict__ b2,
             float* __restrict__ out, int N) {
  int node = (int)((blockIdx.x * 256u + threadIdx.x) >> 6);
  int lane = threadIdx.x & 63;
  if (node >= N) return;
  const float* tr = t + (size_t)node * 256;
  float v = 0.25f * (tr[lane] + tr[64 + lane] + tr[128 + lane] + tr[192 + lane]) + b2[lane];
  v = fmaxf(v, 0.f);
  float mx = v;
  for (int off = 32; off; off >>= 1) mx = fmaxf(mx, __shfl_xor(mx, off));
  float e = __expf(v - mx);
  float sum = e;
  for (int off = 32; off; off >>= 1) sum += __shfl_xor(sum, off);
  out[(size_t)node * 64 + lane] = e / sum;
}

// ---------------------------------------------------------------------------

extern "C" void kernel_launch(void* const* d_in, const int* in_sizes, int n_in,
                              void* d_out, int out_size, void* d_ws, size_t ws_size,
                              hipStream_t stream) {
  const float* x   = (const float*)d_in[0];
  const int*   ei  = (const int*)d_in[1];
  const float* W1  = (const float*)d_in[2];
  const float* as1 = (const float*)d_in[3];
  const float* ad1 = (const float*)d_in[4];
  const float* b1  = (const float*)d_in[5];
  const float* W2  = (const float*)d_in[6];
  const float* as2 = (const float*)d_in[7];
  const float* ad2 = (const float*)d_in[8];
  const float* b2  = (const float*)d_in[9];
  float* out = (float*)d_out;

  const int N = in_sizes[0] / 128;
  const int E = in_sizes[1] / 2;
  const int* srcv = ei;
  const int* dstv = ei + E;

  float* h    = (float*)d_ws;             // [N,256]
  float* hb   = h + (size_t)N * 256;      // [N,256] (layer-1 out / layer-2 temp)
  float* zbuf = hb + (size_t)N * 256;     // 16N: a_s1,a_d1,a_s2,a_d2
  float* a_s1 = zbuf;
  float* a_d1 = a_s1 + (size_t)N * 4;
  float* a_s2 = a_d1 + (size_t)N * 4;
  float* a_d2 = a_s2 + (size_t)N * 4;
  int*   rowptr = (int*)(zbuf + (size_t)N * 16);  // [N+1] (+pad)
  int*   cnt    = rowptr + (N + 4);               // [N]
  int*   cursor = cnt + N;                        // [N]
  int*   col    = cursor + N;                     // [E]
  int*   partials = col + E;                      // [<=256]

  const int nb = (N + 255) / 256;
  const int eb = (E + 255) / 256;

  hipMemsetAsync(cnt, 0, (size_t)N * 4, stream);
  hipMemsetAsync(zbuf, 0, (size_t)N * 16 * 4, stream);
  k_hist<<<eb, 256, 0, stream>>>(dstv, cnt, E);
  k_scan_local<<<nb, 256, 0, stream>>>(cnt, rowptr, partials, N);
  k_scan_part<<<1, 256, 0, stream>>>(partials, nb);
  k_scan_add<<<nb, 256, 0, stream>>>(rowptr, partials, cursor, N, E);
  k_scatter<<<eb, 256, 0, stream>>>(srcv, dstv, cursor, col, E);

  dim3 gg((N + 127) / 128, 2);
  const int ab = ((N + 15) / 16) * 8;  // octet-mapped (node, half) waves
  const int wb = (N + 3) / 4;          // wave-per-node

  k_gemm<<<gg, 256, 0, stream>>>(x, W1, h, N, 128, as1, ad1, a_s1, a_d1);
  k_aggr<1><<<ab, 256, 0, stream>>>(h, rowptr, col, a_s1, a_d1, b1, hb, N);
  k_gemm<<<gg, 256, 0, stream>>>(hb, W2, h, N, 256, as2, ad2, a_s2, a_d2);
  k_aggr<2><<<ab, 256, 0, stream>>>(h, rowptr, col, a_s2, a_d2, b2, hb, N);
  k_final<<<wb, 256, 0, stream>>>(hb, b2, out, N);
}